// Round 8
// baseline (248.452 us; speedup 1.0000x reference)
//
#include <hip/hip_runtime.h>
#include <hip/hip_fp16.h>
#include <math.h>

#define NTOK 2048
#define HID  1024
#define FFN  2048
#define NEXP 8

#define BM 128
#define BN 128
#define BK 32             // fp16 K-step; LDS = 33KB/block -> 4 blocks/CU
#define MAX_TILES 40

// workspace layout (bytes)
#define WS_COUNTS 0
#define WS_SEG    32
#define WS_PROBS  128                       // NTOK*NEXP floats = 64KB
#define WS_LISTS  (128 + NTOK*NEXP*4)       // 8*NTOK ints = 64KB
#define WS_XH     262144                    // [NTOK][HID] fp16 = 4MB
#define WS_W1T    (WS_XH + NTOK*HID*2)      // [E][F][H] fp16 = 32MB
#define WS_W2T    (WS_W1T + NEXP*HID*FFN*2) // [E][H][F] fp16 = 32MB
#define WS_HBUF   (WS_W2T + NEXP*HID*FFN*2) // [5120][FFN] fp16 = 20MB

typedef _Float16 half8 __attribute__((ext_vector_type(8)));
typedef float    f32x4 __attribute__((ext_vector_type(4)));

static __device__ __forceinline__ unsigned short f2h_bits(float f) {
  union { _Float16 h; unsigned short u; } v;
  v.h = (_Float16)f;
  return v.u;
}
static __device__ __forceinline__ unsigned pack2(float a, float b) {
  return (unsigned)f2h_bits(a) | ((unsigned)f2h_bits(b) << 16);
}

#define GLOAD16(gsrc, ldst) \
  __builtin_amdgcn_global_load_lds( \
      (const __attribute__((address_space(1))) unsigned int*)(gsrc), \
      (__attribute__((address_space(3))) unsigned int*)(ldst), 16, 0, 0)

// Drain all outstanding global_load_lds DMA writes issued by this wave.
// (Round-5 lesson: do NOT rely on the compiler's vmcnt before s_barrier.)
#define VMCNT0 asm volatile("s_waitcnt vmcnt(0)" ::: "memory")

// ---------------- fused prep: LDS-free weight transpose | router + x->fp16 ----
// wave-task [0,1024):    w1 [E][H][F] -> w1t [E][F][H] fp16  (e,g,h) tiles
// wave-task [1024,2048): w2 [E][F][H] -> w2t [E][H][F] fp16
// wave-task [2048,4096): router token (task-2048) + xh write
// Transpose wave-task: 64 cols (lane=col) x 256 rows. Reads: 256B/instr
// coalesced (lane i at col g*64+i of row r). After 8 rows each lane holds 8
// consecutive elements of ONE output row -> one 16B store. No LDS/barriers.
__global__ __launch_bounds__(256) void moe_prep(
    const float* __restrict__ x, const float* __restrict__ rw,
    const float* __restrict__ w1, const float* __restrict__ w2,
    unsigned short* __restrict__ xh, unsigned short* __restrict__ w1t,
    unsigned short* __restrict__ w2t,
    int* __restrict__ counts, int* __restrict__ lists, float* __restrict__ probs)
{
  const int tid = threadIdx.x;
  const int wid = tid >> 6, lane = tid & 63;
  const int task = blockIdx.x * 4 + wid;

  if (task < 2048) {
    const float* src; unsigned short* dst; int C, R, g, h;
    if (task < 1024) {                    // w1: R=HID rows, C=FFN cols
      const int e = task >> 7;
      g = (task >> 2) & 31; h = task & 3;
      C = FFN; R = HID;
      src = w1 + (size_t)e * HID * FFN;
      dst = w1t + (size_t)e * HID * FFN;
    } else {                              // w2: R=FFN rows, C=HID cols
      const int u = task - 1024;
      const int e = u >> 7;
      g = (u >> 3) & 15; h = u & 7;
      C = HID; R = FFN;
      src = w2 + (size_t)e * HID * FFN;
      dst = w2t + (size_t)e * HID * FFN;
    }
    const int r0 = h * 256;
    const float* sp = src + (size_t)r0 * C + g*64 + lane;        // lane's column
    unsigned short* dp = dst + (size_t)(g*64 + lane) * R + r0;   // lane's output row
#pragma unroll 4
    for (int rc = 0; rc < 256; rc += 8) {
      const float* q = sp + (size_t)rc * C;
      float v0 = q[0];
      float v1 = q[(size_t)1*C];
      float v2 = q[(size_t)2*C];
      float v3 = q[(size_t)3*C];
      float v4 = q[(size_t)4*C];
      float v5 = q[(size_t)5*C];
      float v6 = q[(size_t)6*C];
      float v7 = q[(size_t)7*C];
      *reinterpret_cast<uint4*>(dp + rc) =
          (uint4){pack2(v0,v1), pack2(v2,v3), pack2(v4,v5), pack2(v6,v7)};
    }
  } else {
    const int t = task - 2048;            // router + xh, one wave per token
    const float* xr = x + (size_t)t * HID + lane * 16;
    const float4* xp = reinterpret_cast<const float4*>(xr);
    float4 v0 = xp[0], v1 = xp[1], v2 = xp[2], v3 = xp[3];
    float xv[16] = {v0.x,v0.y,v0.z,v0.w, v1.x,v1.y,v1.z,v1.w,
                    v2.x,v2.y,v2.z,v2.w, v3.x,v3.y,v3.z,v3.w};
    float acc[NEXP];
#pragma unroll
    for (int e = 0; e < NEXP; ++e) acc[e] = 0.f;
#pragma unroll
    for (int j = 0; j < 16; ++j) {
      const float4* rp = reinterpret_cast<const float4*>(rw + (size_t)(lane*16 + j) * NEXP);
      float4 a = rp[0], b = rp[1];
      acc[0] += xv[j]*a.x; acc[1] += xv[j]*a.y; acc[2] += xv[j]*a.z; acc[3] += xv[j]*a.w;
      acc[4] += xv[j]*b.x; acc[5] += xv[j]*b.y; acc[6] += xv[j]*b.z; acc[7] += xv[j]*b.w;
    }
#pragma unroll
    for (int off = 32; off > 0; off >>= 1) {
#pragma unroll
      for (int e = 0; e < NEXP; ++e) acc[e] += __shfl_down(acc[e], off);
    }
    // xh write (each lane owns 16 contiguous elements)
    unsigned short* xd = xh + (size_t)t * HID + lane * 16;
    *reinterpret_cast<uint4*>(xd) =
        (uint4){pack2(v0.x,v0.y), pack2(v0.z,v0.w), pack2(v1.x,v1.y), pack2(v1.z,v1.w)};
    *reinterpret_cast<uint4*>(xd + 8) =
        (uint4){pack2(v2.x,v2.y), pack2(v2.z,v2.w), pack2(v3.x,v3.y), pack2(v3.z,v3.w)};
    if (lane == 0) {
      float m = acc[0];
#pragma unroll
      for (int e = 1; e < NEXP; ++e) m = fmaxf(m, acc[e]);
      float p[NEXP];
#pragma unroll
      for (int e = 0; e < NEXP; ++e) p[e] = expf(acc[e] - m);
      int i0 = 0;
#pragma unroll
      for (int e = 1; e < NEXP; ++e) if (p[e] > p[i0]) i0 = e;
      int i1 = -1;
#pragma unroll
      for (int e = 0; e < NEXP; ++e) {
        if (e == i0) continue;
        if (i1 < 0 || p[e] > p[i1]) i1 = e;
      }
      const float inv = 1.f / (p[i0] + p[i1]);
      probs[t * NEXP + i0] = p[i0] * inv;
      probs[t * NEXP + i1] = p[i1] * inv;
      int pos0 = atomicAdd(&counts[i0], 1); lists[i0 * NTOK + pos0] = t;
      int pos1 = atomicAdd(&counts[i1], 1); lists[i1 * NTOK + pos1] = t;
    }
  }
}

// ---------------- padded segment offsets ----------------
__global__ void moe_segoff(const int* __restrict__ counts, int* __restrict__ seg) {
  if (threadIdx.x == 0 && blockIdx.x == 0) {
    int run = 0;
    for (int e = 0; e < NEXP; ++e) {
      seg[e] = run;
      run += ((counts[e] + BM - 1) / BM) * BM;
    }
    seg[NEXP] = run;
  }
}

// ---------------- GEMM1: h = gelu(xh[tok] @ w1t[e]^T) -> fp16 hbuf ----------------
__global__ __launch_bounds__(256) void moe_gemm1(
    const unsigned short* __restrict__ xh, const unsigned short* __restrict__ w1t,
    const int* __restrict__ counts, const int* __restrict__ seg,
    const int* __restrict__ lists, unsigned short* __restrict__ hbuf)
{
  const int tile = blockIdx.x >> 4;
  const int jcol = blockIdx.x & 15;
  const int rb = tile * BM;
  if (rb >= seg[NEXP]) return;
  int e = 0;
#pragma unroll
  for (int q = 1; q < NEXP; ++q) if (seg[q] <= rb) e = q;
  const int cnt = counts[e];
  const int rloc0 = rb - seg[e];

  __shared__ int tokL[BM];
  __shared__ __align__(16) unsigned short Asm[2][BM*BK];   // 8KB per buffer
  __shared__ __align__(16) unsigned short Bsm[2][BM*BK];

  const int tid = threadIdx.x;
  if (tid < BM) {
    int rl = rloc0 + tid;
    tokL[tid] = (rl < cnt) ? lists[e * NTOK + rl] : 0;
  }
  __syncthreads();

  const int lane = tid & 63;
  const int wid = tid >> 6;
  const int wr = (wid >> 1) * 64;
  const int wc = (wid & 1) * 64;
  const int lr = (lane >> 4) * 4;
  const int lc = lane & 15;
  const int khi = (lane >> 4) * 8;

  // staging: chunk = i*256 + wid*64 + lane; row = chunk>>2; 16B col = (lane&3)*8 halfwords
  const int cw8 = (lane & 3) * 8;
  const int r0 = wid*16 + (lane >> 2);
  const unsigned short* abase[2];
  const unsigned short* bbase[2];
  abase[0] = xh + (size_t)tokL[r0]      * HID + cw8;
  abase[1] = xh + (size_t)tokL[64 + r0] * HID + cw8;
  bbase[0] = w1t + ((size_t)e * FFN + jcol*BN + r0)      * HID + cw8;
  bbase[1] = w1t + ((size_t)e * FFN + jcol*BN + 64 + r0) * HID + cw8;

  f32x4 acc[4][4];
#pragma unroll
  for (int m = 0; m < 4; ++m)
#pragma unroll
    for (int n = 0; n < 4; ++n)
      acc[m][n] = (f32x4){0.f, 0.f, 0.f, 0.f};

#define STAGE1(buf, kk) do { \
    _Pragma("unroll") \
    for (int i = 0; i < 2; ++i) { \
      GLOAD16(abase[i] + (kk), &Asm[buf][(i*256 + wid*64)*8]); \
      GLOAD16(bbase[i] + (kk), &Bsm[buf][(i*256 + wid*64)*8]); \
    } } while (0)

  STAGE1(0, 0);
  VMCNT0;
  __syncthreads();
  int cur = 0;
  for (int kk = 0; kk < HID; kk += BK) {
    if (kk + BK < HID) STAGE1(cur ^ 1, kk + BK);
    half8 af[4], bf[4];
#pragma unroll
    for (int m = 0; m < 4; ++m)
      af[m] = *reinterpret_cast<const half8*>(&Asm[cur][(wr + m*16 + lc)*BK + khi]);
#pragma unroll
    for (int n = 0; n < 4; ++n)
      bf[n] = *reinterpret_cast<const half8*>(&Bsm[cur][(wc + n*16 + lc)*BK + khi]);
#pragma unroll
    for (int m = 0; m < 4; ++m)
#pragma unroll
      for (int n = 0; n < 4; ++n)
        acc[m][n] = __builtin_amdgcn_mfma_f32_16x16x32_f16(af[m], bf[n], acc[m][n], 0, 0, 0);
    VMCNT0;              // drain next-tile DMA issued above (overlapped with MFMA)
    __syncthreads();
    cur ^= 1;
  }
#undef STAGE1

  // Unconditional writes: padding rows (rl>=cnt) get deterministic values,
  // so gemm2 never reads poison from hbuf.
#pragma unroll
  for (int m = 0; m < 4; ++m) {
#pragma unroll
    for (int r = 0; r < 4; ++r) {
      unsigned short* hp = hbuf + (size_t)(rb + wr + m*16 + lr + r) * FFN + jcol*BN + wc + lc;
#pragma unroll
      for (int n = 0; n < 4; ++n) {
        float v = acc[m][n][r];
        float g = 0.5f * v * (1.f + erff(v * 0.70710678118f));   // exact erf-gelu
        hp[n*16] = f2h_bits(g);
      }
    }
  }
}

// ---------------- GEMM2: out[tok] += p * (hbuf @ w2t[e]^T), split-K x2 ----------------
__global__ __launch_bounds__(256) void moe_gemm2(
    const unsigned short* __restrict__ hbuf, const unsigned short* __restrict__ w2t,
    const int* __restrict__ counts, const int* __restrict__ seg,
    const int* __restrict__ lists, const float* __restrict__ probs,
    float* __restrict__ out)
{
  const int tile = blockIdx.x >> 4;
  const int jcol = (blockIdx.x >> 1) & 7;
  const int ks   = blockIdx.x & 1;
  const int rb = tile * BM;
  if (rb >= seg[NEXP]) return;
  int e = 0;
#pragma unroll
  for (int q = 1; q < NEXP; ++q) if (seg[q] <= rb) e = q;
  const int cnt = counts[e];
  const int rloc0 = rb - seg[e];
  const int k0 = ks * (FFN / 2);
  const int k1 = k0 + (FFN / 2);

  __shared__ int tokL[BM];
  __shared__ float pL[BM];
  __shared__ __align__(16) unsigned short Asm[2][BM*BK];
  __shared__ __align__(16) unsigned short Bsm[2][BM*BK];

  const int tid = threadIdx.x;
  if (tid < BM) {
    int rl = rloc0 + tid;
    if (rl < cnt) {
      int tk = lists[e * NTOK + rl];
      tokL[tid] = tk;
      pL[tid] = probs[tk * NEXP + e];
    } else { tokL[tid] = 0; pL[tid] = 0.f; }
  }
  __syncthreads();

  const int lane = tid & 63;
  const int wid = tid >> 6;
  const int wr = (wid >> 1) * 64;
  const int wc = (wid & 1) * 64;
  const int lr = (lane >> 4) * 4;
  const int lc = lane & 15;
  const int khi = (lane >> 4) * 8;

  const int cw8 = (lane & 3) * 8;
  const int r0 = wid*16 + (lane >> 2);
  const unsigned short* abase[2];
  const unsigned short* bbase[2];
  abase[0] = hbuf + (size_t)(rb + r0)      * FFN + cw8;
  abase[1] = hbuf + (size_t)(rb + 64 + r0) * FFN + cw8;
  bbase[0] = w2t + ((size_t)e * HID + jcol*BN + r0)      * FFN + cw8;
  bbase[1] = w2t + ((size_t)e * HID + jcol*BN + 64 + r0) * FFN + cw8;

  f32x4 acc[4][4];
#pragma unroll
  for (int m = 0; m < 4; ++m)
#pragma unroll
    for (int n = 0; n < 4; ++n)
      acc[m][n] = (f32x4){0.f, 0.f, 0.f, 0.f};

#define STAGE2(buf, kk) do { \
    _Pragma("unroll") \
    for (int i = 0; i < 2; ++i) { \
      GLOAD16(abase[i] + (kk), &Asm[buf][(i*256 + wid*64)*8]); \
      GLOAD16(bbase[i] + (kk), &Bsm[buf][(i*256 + wid*64)*8]); \
    } } while (0)

  STAGE2(0, k0);
  VMCNT0;
  __syncthreads();
  int cur = 0;
  for (int kk = k0; kk < k1; kk += BK) {
    if (kk + BK < k1) STAGE2(cur ^ 1, kk + BK);
    half8 af[4], bf[4];
#pragma unroll
    for (int m = 0; m < 4; ++m)
      af[m] = *reinterpret_cast<const half8*>(&Asm[cur][(wr + m*16 + lc)*BK + khi]);
#pragma unroll
    for (int n = 0; n < 4; ++n)
      bf[n] = *reinterpret_cast<const half8*>(&Bsm[cur][(wc + n*16 + lc)*BK + khi]);
#pragma unroll
    for (int m = 0; m < 4; ++m)
#pragma unroll
      for (int n = 0; n < 4; ++n)
        acc[m][n] = __builtin_amdgcn_mfma_f32_16x16x32_f16(af[m], bf[n], acc[m][n], 0, 0, 0);
    VMCNT0;              // drain next-tile DMA issued above
    __syncthreads();
    cur ^= 1;
  }
#undef STAGE2

#pragma unroll
  for (int m = 0; m < 4; ++m) {
#pragma unroll
    for (int r = 0; r < 4; ++r) {
      const int lrow = wr + m*16 + lr + r;
      const int rl = rloc0 + lrow;
      if (rl >= cnt) continue;
      const int tok = tokL[lrow];
      const float p = pL[lrow];
      float* op = out + (size_t)tok * HID + jcol*BN + wc + lc;
#pragma unroll
      for (int n = 0; n < 4; ++n)
        atomicAdd(&op[n*16], p * acc[m][n][r]);   // <=4 commutative fp32 adds/element
    }
  }
}

extern "C" void kernel_launch(void* const* d_in, const int* in_sizes, int n_in,
                              void* d_out, int out_size, void* d_ws, size_t ws_size,
                              hipStream_t stream) {
  const float* x  = (const float*)d_in[0];
  const float* rw = (const float*)d_in[1];
  const float* w1 = (const float*)d_in[2];
  const float* w2 = (const float*)d_in[3];
  float* out = (float*)d_out;

  char* ws = (char*)d_ws;
  int*   counts = (int*)(ws + WS_COUNTS);
  int*   seg    = (int*)(ws + WS_SEG);
  float* probs  = (float*)(ws + WS_PROBS);
  int*   lists  = (int*)(ws + WS_LISTS);
  unsigned short* xh   = (unsigned short*)(ws + WS_XH);
  unsigned short* w1t  = (unsigned short*)(ws + WS_W1T);
  unsigned short* w2t  = (unsigned short*)(ws + WS_W2T);
  unsigned short* hbuf = (unsigned short*)(ws + WS_HBUF);

  hipMemsetAsync(ws, 0, 128, stream);                                   // counts+seg
  hipMemsetAsync(d_out, 0, (size_t)NTOK * HID * sizeof(float), stream); // atomic target

  moe_prep<<<1024, 256, 0, stream>>>(x, rw, w1, w2, xh, w1t, w2t,
                                     counts, lists, probs);
  moe_segoff<<<1, 64, 0, stream>>>(counts, seg);
  moe_gemm1<<<MAX_TILES * (FFN / BN), 256, 0, stream>>>(xh, w1t, counts, seg, lists, hbuf);
  moe_gemm2<<<MAX_TILES * (HID / BN) * 2, 256, 0, stream>>>(hbuf, w2t, counts, seg, lists, probs, out);
}

// Round 9
// 191.783 us; speedup vs baseline: 1.2955x; 1.2955x over previous
//
#include <hip/hip_runtime.h>
#include <hip/hip_fp16.h>
#include <math.h>

#define NTOK 2048
#define HID  1024
#define FFN  2048
#define NEXP 8

#define BM 128
#define BN 128
#define BK 32
#define LDA 36            // halfwords; 72B row stride = 18 banks -> 16 lanes, 16 distinct banks
#define MAX_TILES 40

// workspace layout (bytes)
#define WS_COUNTS 0
#define WS_SEG    32
#define WS_PROBS  128                       // NTOK*NEXP floats = 64KB
#define WS_LISTS  (128 + NTOK*NEXP*4)       // 8*NTOK ints = 64KB
#define WS_XH     262144                    // [NTOK][HID] fp16 = 4MB
#define WS_HBUF   (WS_XH + NTOK*HID*2)      // [5120][FFN] fp16 = 20MB

typedef _Float16 half8 __attribute__((ext_vector_type(8)));
typedef float    f32x4 __attribute__((ext_vector_type(4)));
typedef unsigned long ulong2_t __attribute__((ext_vector_type(2)));

static __device__ __forceinline__ unsigned short f2h_bits(float f) {
  union { _Float16 h; unsigned short u; } v;
  v.h = (_Float16)f;
  return v.u;
}
static __device__ __forceinline__ unsigned pack2(float a, float b) {
  return (unsigned)f2h_bits(a) | ((unsigned)f2h_bits(b) << 16);
}
static __device__ __forceinline__ half8 frag_ld(const unsigned short* p) {
  union { ulong2_t u; half8 h; } t;
  t.u.x = *reinterpret_cast<const unsigned long*>(p);
  t.u.y = *reinterpret_cast<const unsigned long*>(p + 4);
  return t.h;
}

// ---------------- prep: router + x->fp16 (one wave per token) ----------------
__global__ __launch_bounds__(256) void moe_prep(
    const float* __restrict__ x, const float* __restrict__ rw,
    unsigned short* __restrict__ xh,
    int* __restrict__ counts, int* __restrict__ lists, float* __restrict__ probs)
{
  const int tid = threadIdx.x;
  const int wid = tid >> 6, lane = tid & 63;
  const int t = blockIdx.x * 4 + wid;

  const float* xr = x + (size_t)t * HID + lane * 16;
  const float4* xp = reinterpret_cast<const float4*>(xr);
  float4 v0 = xp[0], v1 = xp[1], v2 = xp[2], v3 = xp[3];
  float xv[16] = {v0.x,v0.y,v0.z,v0.w, v1.x,v1.y,v1.z,v1.w,
                  v2.x,v2.y,v2.z,v2.w, v3.x,v3.y,v3.z,v3.w};
  float acc[NEXP];
#pragma unroll
  for (int e = 0; e < NEXP; ++e) acc[e] = 0.f;
#pragma unroll
  for (int j = 0; j < 16; ++j) {
    const float4* rp = reinterpret_cast<const float4*>(rw + (size_t)(lane*16 + j) * NEXP);
    float4 a = rp[0], b = rp[1];
    acc[0] += xv[j]*a.x; acc[1] += xv[j]*a.y; acc[2] += xv[j]*a.z; acc[3] += xv[j]*a.w;
    acc[4] += xv[j]*b.x; acc[5] += xv[j]*b.y; acc[6] += xv[j]*b.z; acc[7] += xv[j]*b.w;
  }
#pragma unroll
  for (int off = 32; off > 0; off >>= 1) {
#pragma unroll
    for (int e = 0; e < NEXP; ++e) acc[e] += __shfl_down(acc[e], off);
  }
  unsigned short* xd = xh + (size_t)t * HID + lane * 16;
  *reinterpret_cast<uint4*>(xd) =
      (uint4){pack2(v0.x,v0.y), pack2(v0.z,v0.w), pack2(v1.x,v1.y), pack2(v1.z,v1.w)};
  *reinterpret_cast<uint4*>(xd + 8) =
      (uint4){pack2(v2.x,v2.y), pack2(v2.z,v2.w), pack2(v3.x,v3.y), pack2(v3.z,v3.w)};
  if (lane == 0) {
    float m = acc[0];
#pragma unroll
    for (int e = 1; e < NEXP; ++e) m = fmaxf(m, acc[e]);
    float p[NEXP];
#pragma unroll
    for (int e = 0; e < NEXP; ++e) p[e] = expf(acc[e] - m);
    int i0 = 0;
#pragma unroll
    for (int e = 1; e < NEXP; ++e) if (p[e] > p[i0]) i0 = e;
    int i1 = -1;
#pragma unroll
    for (int e = 0; e < NEXP; ++e) {
      if (e == i0) continue;
      if (i1 < 0 || p[e] > p[i1]) i1 = e;
    }
    const float inv = 1.f / (p[i0] + p[i1]);
    probs[t * NEXP + i0] = p[i0] * inv;
    probs[t * NEXP + i1] = p[i1] * inv;
    int pos0 = atomicAdd(&counts[i0], 1); lists[i0 * NTOK + pos0] = t;
    int pos1 = atomicAdd(&counts[i1], 1); lists[i1 * NTOK + pos1] = t;
  }
}

// ---------------- padded segment offsets ----------------
__global__ void moe_segoff(const int* __restrict__ counts, int* __restrict__ seg) {
  if (threadIdx.x == 0 && blockIdx.x == 0) {
    int run = 0;
    for (int e = 0; e < NEXP; ++e) {
      seg[e] = run;
      run += ((counts[e] + BM - 1) / BM) * BM;
    }
    seg[NEXP] = run;
  }
}

// ---------------- GEMM1: h = gelu(xh[tok] @ w1[e]) -> fp16 hbuf ----------------
// A: fp16 gathered rows, reg-staged. B: fp32 weights read DIRECTLY (no pre-
// transpose), converted to fp16 in-reg, transposed into Bsm[col][k] via
// per-column b64 writes (lane=col -> coalesced global, conflict-free LDS).
__global__ __launch_bounds__(256) void moe_gemm1(
    const unsigned short* __restrict__ xh, const float* __restrict__ w1,
    const int* __restrict__ counts, const int* __restrict__ seg,
    const int* __restrict__ lists, unsigned short* __restrict__ hbuf)
{
  const int tile = blockIdx.x >> 4;
  const int jcol = blockIdx.x & 15;
  const int rb = tile * BM;
  if (rb >= seg[NEXP]) return;
  int e = 0;
#pragma unroll
  for (int q = 1; q < NEXP; ++q) if (seg[q] <= rb) e = q;
  const int cnt = counts[e];
  const int rloc0 = rb - seg[e];

  __shared__ int tokL[BM];
  __shared__ unsigned short Asm[2][BM*LDA];   // 9216B each
  __shared__ unsigned short Bsm[2][BM*LDA];

  const int tid = threadIdx.x;
  if (tid < BM) {
    int rl = rloc0 + tid;
    tokL[tid] = (rl < cnt) ? lists[e * NTOK + rl] : 0;
  }
  __syncthreads();

  const int lane = tid & 63;
  const int wid = tid >> 6;
  const int wr = (wid >> 1) * 64;
  const int wc = (wid & 1) * 64;
  const int lr = (lane >> 4) * 4;
  const int lc = lane & 15;
  const int khi = (lane >> 4) * 8;

  // A staging: row = tid>>1, k-half = (tid&1)*16 (2x dwordx4 fp16 per thread)
  const int ra  = tid >> 1;
  const int kha = (tid & 1) * 16;
  const unsigned short* asrc = xh + (size_t)tokL[ra] * HID + kha;
  // B staging: col = (wid&1)*64 + lane (coalesced), k-octets (wid>>1)*2 + it
  const int colB  = (wid & 1) * 64 + lane;
  const int koctB = (wid >> 1) * 2;
  const float* bsrc = w1 + (size_t)e * HID * FFN + (size_t)jcol * BN + colB;

  f32x4 acc[4][4];
#pragma unroll
  for (int m = 0; m < 4; ++m)
#pragma unroll
    for (int n = 0; n < 4; ++n)
      acc[m][n] = (f32x4){0.f, 0.f, 0.f, 0.f};

  uint4 av0, av1;
  float bv[16];

#define LOADT1(kk) do { \
    av0 = *reinterpret_cast<const uint4*>(asrc + (kk)); \
    av1 = *reinterpret_cast<const uint4*>(asrc + (kk) + 8); \
    _Pragma("unroll") \
    for (int it = 0; it < 2; ++it) \
      _Pragma("unroll") \
      for (int j = 0; j < 8; ++j) \
        bv[it*8+j] = bsrc[(size_t)((kk) + (koctB+it)*8 + j) * FFN]; \
  } while (0)

#define STORET(buf) do { \
    const int ai = ra*LDA + kha; \
    *reinterpret_cast<uint2*>(&Asm[buf][ai])      = (uint2){av0.x, av0.y}; \
    *reinterpret_cast<uint2*>(&Asm[buf][ai + 4])  = (uint2){av0.z, av0.w}; \
    *reinterpret_cast<uint2*>(&Asm[buf][ai + 8])  = (uint2){av1.x, av1.y}; \
    *reinterpret_cast<uint2*>(&Asm[buf][ai + 12]) = (uint2){av1.z, av1.w}; \
    _Pragma("unroll") \
    for (int it = 0; it < 2; ++it) { \
      const int bi = colB*LDA + (koctB+it)*8; \
      *reinterpret_cast<uint2*>(&Bsm[buf][bi]) = \
          (uint2){pack2(bv[it*8+0],bv[it*8+1]), pack2(bv[it*8+2],bv[it*8+3])}; \
      *reinterpret_cast<uint2*>(&Bsm[buf][bi+4]) = \
          (uint2){pack2(bv[it*8+4],bv[it*8+5]), pack2(bv[it*8+6],bv[it*8+7])}; \
    } } while (0)

  LOADT1(0);
  int cur = 0;
  for (int kk = 0; kk < HID; kk += BK) {
    STORET(cur);
    __syncthreads();
    if (kk + BK < HID) LOADT1(kk + BK);   // issue early; hides under MFMA
    half8 af[4], bf[4];
#pragma unroll
    for (int m = 0; m < 4; ++m)
      af[m] = frag_ld(&Asm[cur][(wr + m*16 + lc)*LDA + khi]);
#pragma unroll
    for (int n = 0; n < 4; ++n)
      bf[n] = frag_ld(&Bsm[cur][(wc + n*16 + lc)*LDA + khi]);
#pragma unroll
    for (int m = 0; m < 4; ++m)
#pragma unroll
      for (int n = 0; n < 4; ++n)
        acc[m][n] = __builtin_amdgcn_mfma_f32_16x16x32_f16(af[m], bf[n], acc[m][n], 0, 0, 0);
    cur ^= 1;
  }
#undef LOADT1

  // Unconditional: padding rows get deterministic values (token-0 data),
  // so gemm2 never reads poison from hbuf.
#pragma unroll
  for (int m = 0; m < 4; ++m) {
#pragma unroll
    for (int r = 0; r < 4; ++r) {
      unsigned short* hp = hbuf + (size_t)(rb + wr + m*16 + lr + r) * FFN + jcol*BN + wc + lc;
#pragma unroll
      for (int n = 0; n < 4; ++n) {
        float v = acc[m][n][r];
        float g = 0.5f * v * (1.f + erff(v * 0.70710678118f));   // exact erf-gelu
        hp[n*16] = f2h_bits(g);
      }
    }
  }
}

// ---------------- GEMM2: out[tok] += p * (hbuf @ w2[e]), split-K x2 ----------------
__global__ __launch_bounds__(256) void moe_gemm2(
    const unsigned short* __restrict__ hbuf, const float* __restrict__ w2,
    const int* __restrict__ counts, const int* __restrict__ seg,
    const int* __restrict__ lists, const float* __restrict__ probs,
    float* __restrict__ out)
{
  const int tile = blockIdx.x >> 4;
  const int jcol = (blockIdx.x >> 1) & 7;
  const int ks   = blockIdx.x & 1;
  const int rb = tile * BM;
  if (rb >= seg[NEXP]) return;
  int e = 0;
#pragma unroll
  for (int q = 1; q < NEXP; ++q) if (seg[q] <= rb) e = q;
  const int cnt = counts[e];
  const int rloc0 = rb - seg[e];
  const int k0 = ks * (FFN / 2);
  const int k1 = k0 + (FFN / 2);

  __shared__ int tokL[BM];
  __shared__ float pL[BM];
  __shared__ unsigned short Asm[2][BM*LDA];
  __shared__ unsigned short Bsm[2][BM*LDA];

  const int tid = threadIdx.x;
  if (tid < BM) {
    int rl = rloc0 + tid;
    if (rl < cnt) {
      int tk = lists[e * NTOK + rl];
      tokL[tid] = tk;
      pL[tid] = probs[tk * NEXP + e];
    } else { tokL[tid] = 0; pL[tid] = 0.f; }
  }
  __syncthreads();

  const int lane = tid & 63;
  const int wid = tid >> 6;
  const int wr = (wid >> 1) * 64;
  const int wc = (wid & 1) * 64;
  const int lr = (lane >> 4) * 4;
  const int lc = lane & 15;
  const int khi = (lane >> 4) * 8;

  const int ra  = tid >> 1;
  const int kha = (tid & 1) * 16;
  const unsigned short* asrc = hbuf + (size_t)(rb + ra) * FFN + kha;
  const int colB  = (wid & 1) * 64 + lane;
  const int koctB = (wid >> 1) * 2;
  const float* bsrc = w2 + (size_t)e * FFN * HID + (size_t)jcol * BN + colB;

  f32x4 acc[4][4];
#pragma unroll
  for (int m = 0; m < 4; ++m)
#pragma unroll
    for (int n = 0; n < 4; ++n)
      acc[m][n] = (f32x4){0.f, 0.f, 0.f, 0.f};

  uint4 av0, av1;
  float bv[16];

#define LOADT2(kk) do { \
    av0 = *reinterpret_cast<const uint4*>(asrc + (kk)); \
    av1 = *reinterpret_cast<const uint4*>(asrc + (kk) + 8); \
    _Pragma("unroll") \
    for (int it = 0; it < 2; ++it) \
      _Pragma("unroll") \
      for (int j = 0; j < 8; ++j) \
        bv[it*8+j] = bsrc[(size_t)((kk) + (koctB+it)*8 + j) * HID]; \
  } while (0)

  LOADT2(k0);
  int cur = 0;
  for (int kk = k0; kk < k1; kk += BK) {
    STORET(cur);
    __syncthreads();
    if (kk + BK < k1) LOADT2(kk + BK);
    half8 af[4], bf[4];
#pragma unroll
    for (int m = 0; m < 4; ++m)
      af[m] = frag_ld(&Asm[cur][(wr + m*16 + lc)*LDA + khi]);
#pragma unroll
    for (int n = 0; n < 4; ++n)
      bf[n] = frag_ld(&Bsm[cur][(wc + n*16 + lc)*LDA + khi]);
#pragma unroll
    for (int m = 0; m < 4; ++m)
#pragma unroll
      for (int n = 0; n < 4; ++n)
        acc[m][n] = __builtin_amdgcn_mfma_f32_16x16x32_f16(af[m], bf[n], acc[m][n], 0, 0, 0);
    cur ^= 1;
  }
#undef LOADT2
#undef STORET

#pragma unroll
  for (int m = 0; m < 4; ++m) {
#pragma unroll
    for (int r = 0; r < 4; ++r) {
      const int lrow = wr + m*16 + lr + r;
      const int rl = rloc0 + lrow;
      if (rl >= cnt) continue;
      const int tok = tokL[lrow];
      const float p = pL[lrow];
      float* op = out + (size_t)tok * HID + jcol*BN + wc + lc;
#pragma unroll
      for (int n = 0; n < 4; ++n)
        atomicAdd(&op[n*16], p * acc[m][n][r]);   // <=4 commutative fp32 adds/element
    }
  }
}

extern "C" void kernel_launch(void* const* d_in, const int* in_sizes, int n_in,
                              void* d_out, int out_size, void* d_ws, size_t ws_size,
                              hipStream_t stream) {
  const float* x  = (const float*)d_in[0];
  const float* rw = (const float*)d_in[1];
  const float* w1 = (const float*)d_in[2];
  const float* w2 = (const float*)d_in[3];
  float* out = (float*)d_out;

  char* ws = (char*)d_ws;
  int*   counts = (int*)(ws + WS_COUNTS);
  int*   seg    = (int*)(ws + WS_SEG);
  float* probs  = (float*)(ws + WS_PROBS);
  int*   lists  = (int*)(ws + WS_LISTS);
  unsigned short* xh   = (unsigned short*)(ws + WS_XH);
  unsigned short* hbuf = (unsigned short*)(ws + WS_HBUF);

  hipMemsetAsync(ws, 0, 128, stream);                                   // counts+seg
  hipMemsetAsync(d_out, 0, (size_t)NTOK * HID * sizeof(float), stream); // atomic target

  moe_prep<<<NTOK/4, 256, 0, stream>>>(x, rw, xh, counts, lists, probs);
  moe_segoff<<<1, 64, 0, stream>>>(counts, seg);
  moe_gemm1<<<MAX_TILES * (FFN / BN), 256, 0, stream>>>(xh, w1, counts, seg, lists, hbuf);
  moe_gemm2<<<MAX_TILES * (HID / BN) * 2, 256, 0, stream>>>(hbuf, w2, counts, seg, lists, probs, out);
}

// Round 10
// 191.624 us; speedup vs baseline: 1.2966x; 1.0008x over previous
//
#include <hip/hip_runtime.h>
#include <hip/hip_fp16.h>
#include <math.h>

#define NTOK 2048
#define HID  1024
#define FFN  2048
#define NEXP 8

#define BM 128
#define BN 128
#define BK 32             // fp16 K-step; LDS = 33KB/block -> 4 blocks/CU
#define MAX_TILES 40
#define TLDA 66           // transpose LDS stride (hw): 33 dwords -> +1 bank/row

// workspace layout (bytes)
#define WS_COUNTS 0
#define WS_SEG    32
#define WS_PROBS  128                       // NTOK*NEXP floats = 64KB
#define WS_LISTS  (128 + NTOK*NEXP*4)       // 8*NTOK ints = 64KB
#define WS_XH     262144                    // [NTOK][HID] fp16 = 4MB
#define WS_W1T    (WS_XH + NTOK*HID*2)      // [E][F][H] fp16 = 32MB
#define WS_W2T    (WS_W1T + NEXP*HID*FFN*2) // [E][H][F] fp16 = 32MB
#define WS_HBUF   (WS_W2T + NEXP*HID*FFN*2) // [5120][FFN] fp16 = 20MB

typedef _Float16 half8 __attribute__((ext_vector_type(8)));
typedef float    f32x4 __attribute__((ext_vector_type(4)));

static __device__ __forceinline__ unsigned short f2h_bits(float f) {
  union { _Float16 h; unsigned short u; } v;
  v.h = (_Float16)f;
  return v.u;
}
static __device__ __forceinline__ unsigned pack2(float a, float b) {
  return (unsigned)f2h_bits(a) | ((unsigned)f2h_bits(b) << 16);
}

#define GLOAD16(gsrc, ldst) \
  __builtin_amdgcn_global_load_lds( \
      (const __attribute__((address_space(1))) unsigned int*)(gsrc), \
      (__attribute__((address_space(3))) unsigned int*)(ldst), 16, 0, 0)

// Drain all outstanding global_load_lds DMA writes issued by this wave.
// (Round-5 lesson: do NOT rely on the compiler's vmcnt before s_barrier.)
#define VMCNT0 asm volatile("s_waitcnt vmcnt(0)" ::: "memory")

// ---------------- fused prep: 64x64 LDS transpose tiles | router + x->fp16 ----
// bid [0,4096):    w1 [E][1024][2048] -> w1t [E][2048][1024] fp16
// bid [4096,8192): w2 [E][2048][1024] -> w2t [E][1024][2048] fp16
// bid [8192,8704): router, 4 tokens/block (1 wave each) + xh write
// Transpose tile: read 4xfloat4/thread (coalesced), ds_write_b32 @ stride-66hw
// (33 dwords: +1 bank per row, ~2-way worst). Write side: thread owns output
// row c, 16 ds_read_u16 (lanes at fixed j = 32 consecutive dwords = banks
// 0..31), 2x dwordx4 contiguous stores (no partial-line write amplification).
__global__ __launch_bounds__(256) void moe_prep(
    const float* __restrict__ x, const float* __restrict__ rw,
    const float* __restrict__ w1, const float* __restrict__ w2,
    unsigned short* __restrict__ xh, unsigned short* __restrict__ w1t,
    unsigned short* __restrict__ w2t,
    int* __restrict__ counts, int* __restrict__ lists, float* __restrict__ probs)
{
  __shared__ unsigned short Ls[64 * TLDA];
  const int bid = blockIdx.x;
  const int tid = threadIdx.x;

  if (bid < 8192) {
    const float* src; unsigned short* dst; int C, R, r0, c0;
    if (bid < 4096) {                     // w1: 1024 rows x 2048 cols
      const int e = bid >> 9, rem = bid & 511;
      R = HID; C = FFN;
      r0 = (rem >> 5) * 64; c0 = (rem & 31) * 64;
      src = w1 + (size_t)e * HID * FFN;
      dst = w1t + (size_t)e * HID * FFN;
    } else {                              // w2: 2048 rows x 1024 cols
      const int u = bid - 4096;
      const int e = u >> 9, rem = u & 511;
      R = FFN; C = HID;
      r0 = (rem >> 4) * 64; c0 = (rem & 15) * 64;
      src = w2 + (size_t)e * HID * FFN;
      dst = w2t + (size_t)e * HID * FFN;
    }
    // read phase: row = tid>>2, 16 cols at (tid&3)*16
    {
      const int row = tid >> 2, cq = tid & 3;
      const float4* sp = reinterpret_cast<const float4*>(
          src + (size_t)(r0 + row) * C + c0 + cq * 16);
      float4 a = sp[0], b = sp[1], c = sp[2], d = sp[3];
      unsigned pk[8] = {pack2(a.x,a.y), pack2(a.z,a.w), pack2(b.x,b.y), pack2(b.z,b.w),
                        pack2(c.x,c.y), pack2(c.z,c.w), pack2(d.x,d.y), pack2(d.z,d.w)};
      unsigned* Ld = reinterpret_cast<unsigned*>(Ls);
      const int dbase = row * (TLDA/2) + cq * 8;     // dword index; TLDA/2=33
#pragma unroll
      for (int j = 0; j < 8; ++j) Ld[dbase + j] = pk[j];
    }
    __syncthreads();
    // write phase: output row c = tid>>2, rows rs*16..+15
    {
      const int c = tid >> 2, rs = tid & 3;
      unsigned v[8];
#pragma unroll
      for (int j = 0; j < 8; ++j) {
        unsigned lo = Ls[(rs*16 + 2*j    ) * TLDA + c];
        unsigned hi = Ls[(rs*16 + 2*j + 1) * TLDA + c];
        v[j] = lo | (hi << 16);
      }
      unsigned short* dp = dst + (size_t)(c0 + c) * R + r0 + rs * 16;
      *reinterpret_cast<uint4*>(dp)     = (uint4){v[0], v[1], v[2], v[3]};
      *reinterpret_cast<uint4*>(dp + 8) = (uint4){v[4], v[5], v[6], v[7]};
    }
  } else {
    const int wid = tid >> 6, lane = tid & 63;
    const int t = (bid - 8192) * 4 + wid;
    const float* xr = x + (size_t)t * HID + lane * 16;
    const float4* xp = reinterpret_cast<const float4*>(xr);
    float4 v0 = xp[0], v1 = xp[1], v2 = xp[2], v3 = xp[3];
    float xv[16] = {v0.x,v0.y,v0.z,v0.w, v1.x,v1.y,v1.z,v1.w,
                    v2.x,v2.y,v2.z,v2.w, v3.x,v3.y,v3.z,v3.w};
    float acc[NEXP];
#pragma unroll
    for (int e = 0; e < NEXP; ++e) acc[e] = 0.f;
#pragma unroll
    for (int j = 0; j < 16; ++j) {
      const float4* rp = reinterpret_cast<const float4*>(rw + (size_t)(lane*16 + j) * NEXP);
      float4 a = rp[0], b = rp[1];
      acc[0] += xv[j]*a.x; acc[1] += xv[j]*a.y; acc[2] += xv[j]*a.z; acc[3] += xv[j]*a.w;
      acc[4] += xv[j]*b.x; acc[5] += xv[j]*b.y; acc[6] += xv[j]*b.z; acc[7] += xv[j]*b.w;
    }
#pragma unroll
    for (int off = 32; off > 0; off >>= 1) {
#pragma unroll
      for (int e = 0; e < NEXP; ++e) acc[e] += __shfl_down(acc[e], off);
    }
    unsigned short* xd = xh + (size_t)t * HID + lane * 16;
    *reinterpret_cast<uint4*>(xd) =
        (uint4){pack2(v0.x,v0.y), pack2(v0.z,v0.w), pack2(v1.x,v1.y), pack2(v1.z,v1.w)};
    *reinterpret_cast<uint4*>(xd + 8) =
        (uint4){pack2(v2.x,v2.y), pack2(v2.z,v2.w), pack2(v3.x,v3.y), pack2(v3.z,v3.w)};
    if (lane == 0) {
      float m = acc[0];
#pragma unroll
      for (int e = 1; e < NEXP; ++e) m = fmaxf(m, acc[e]);
      float p[NEXP];
#pragma unroll
      for (int e = 0; e < NEXP; ++e) p[e] = expf(acc[e] - m);
      int i0 = 0;
#pragma unroll
      for (int e = 1; e < NEXP; ++e) if (p[e] > p[i0]) i0 = e;
      int i1 = -1;
#pragma unroll
      for (int e = 0; e < NEXP; ++e) {
        if (e == i0) continue;
        if (i1 < 0 || p[e] > p[i1]) i1 = e;
      }
      const float inv = 1.f / (p[i0] + p[i1]);
      probs[t * NEXP + i0] = p[i0] * inv;
      probs[t * NEXP + i1] = p[i1] * inv;
      int pos0 = atomicAdd(&counts[i0], 1); lists[i0 * NTOK + pos0] = t;
      int pos1 = atomicAdd(&counts[i1], 1); lists[i1 * NTOK + pos1] = t;
    }
  }
}

// ---------------- padded segment offsets ----------------
__global__ void moe_segoff(const int* __restrict__ counts, int* __restrict__ seg) {
  if (threadIdx.x == 0 && blockIdx.x == 0) {
    int run = 0;
    for (int e = 0; e < NEXP; ++e) {
      seg[e] = run;
      run += ((counts[e] + BM - 1) / BM) * BM;
    }
    seg[NEXP] = run;
  }
}

// ---------------- GEMM1: h = gelu(xh[tok] @ w1t[e]^T) -> fp16 hbuf ----------------
__global__ __launch_bounds__(256) void moe_gemm1(
    const unsigned short* __restrict__ xh, const unsigned short* __restrict__ w1t,
    const int* __restrict__ counts, const int* __restrict__ seg,
    const int* __restrict__ lists, unsigned short* __restrict__ hbuf)
{
  const int tile = blockIdx.x >> 4;
  const int jcol = blockIdx.x & 15;
  const int rb = tile * BM;
  if (rb >= seg[NEXP]) return;
  int e = 0;
#pragma unroll
  for (int q = 1; q < NEXP; ++q) if (seg[q] <= rb) e = q;
  const int cnt = counts[e];
  const int rloc0 = rb - seg[e];

  __shared__ int tokL[BM];
  __shared__ __align__(16) unsigned short Asm[2][BM*BK];   // 8KB per buffer
  __shared__ __align__(16) unsigned short Bsm[2][BM*BK];

  const int tid = threadIdx.x;
  if (tid < BM) {
    int rl = rloc0 + tid;
    tokL[tid] = (rl < cnt) ? lists[e * NTOK + rl] : 0;
  }
  __syncthreads();

  const int lane = tid & 63;
  const int wid = tid >> 6;
  const int wr = (wid >> 1) * 64;
  const int wc = (wid & 1) * 64;
  const int lr = (lane >> 4) * 4;
  const int lc = lane & 15;
  const int khi = (lane >> 4) * 8;

  const int cw8 = (lane & 3) * 8;
  const int r0 = wid*16 + (lane >> 2);
  const unsigned short* abase[2];
  const unsigned short* bbase[2];
  abase[0] = xh + (size_t)tokL[r0]      * HID + cw8;
  abase[1] = xh + (size_t)tokL[64 + r0] * HID + cw8;
  bbase[0] = w1t + ((size_t)e * FFN + jcol*BN + r0)      * HID + cw8;
  bbase[1] = w1t + ((size_t)e * FFN + jcol*BN + 64 + r0) * HID + cw8;

  f32x4 acc[4][4];
#pragma unroll
  for (int m = 0; m < 4; ++m)
#pragma unroll
    for (int n = 0; n < 4; ++n)
      acc[m][n] = (f32x4){0.f, 0.f, 0.f, 0.f};

#define STAGE1(buf, kk) do { \
    _Pragma("unroll") \
    for (int i = 0; i < 2; ++i) { \
      GLOAD16(abase[i] + (kk), &Asm[buf][(i*256 + wid*64)*8]); \
      GLOAD16(bbase[i] + (kk), &Bsm[buf][(i*256 + wid*64)*8]); \
    } } while (0)

  STAGE1(0, 0);
  VMCNT0;
  __syncthreads();
  int cur = 0;
  for (int kk = 0; kk < HID; kk += BK) {
    if (kk + BK < HID) STAGE1(cur ^ 1, kk + BK);
    half8 af[4], bf[4];
#pragma unroll
    for (int m = 0; m < 4; ++m)
      af[m] = *reinterpret_cast<const half8*>(&Asm[cur][(wr + m*16 + lc)*BK + khi]);
#pragma unroll
    for (int n = 0; n < 4; ++n)
      bf[n] = *reinterpret_cast<const half8*>(&Bsm[cur][(wc + n*16 + lc)*BK + khi]);
#pragma unroll
    for (int m = 0; m < 4; ++m)
#pragma unroll
      for (int n = 0; n < 4; ++n)
        acc[m][n] = __builtin_amdgcn_mfma_f32_16x16x32_f16(af[m], bf[n], acc[m][n], 0, 0, 0);
    VMCNT0;              // drain next-tile DMA issued above (overlapped with MFMA)
    __syncthreads();
    cur ^= 1;
  }
#undef STAGE1

  // Unconditional: padding rows get deterministic values (token-0 data),
  // so gemm2 never reads poison from hbuf.
#pragma unroll
  for (int m = 0; m < 4; ++m) {
#pragma unroll
    for (int r = 0; r < 4; ++r) {
      unsigned short* hp = hbuf + (size_t)(rb + wr + m*16 + lr + r) * FFN + jcol*BN + wc + lc;
#pragma unroll
      for (int n = 0; n < 4; ++n) {
        float v = acc[m][n][r];
        float g = 0.5f * v * (1.f + erff(v * 0.70710678118f));   // exact erf-gelu
        hp[n*16] = f2h_bits(g);
      }
    }
  }
}

// ---------------- GEMM2: out[tok] += p * (hbuf @ w2t[e]^T), split-K x2 ----------------
__global__ __launch_bounds__(256) void moe_gemm2(
    const unsigned short* __restrict__ hbuf, const unsigned short* __restrict__ w2t,
    const int* __restrict__ counts, const int* __restrict__ seg,
    const int* __restrict__ lists, const float* __restrict__ probs,
    float* __restrict__ out)
{
  const int tile = blockIdx.x >> 4;
  const int jcol = (blockIdx.x >> 1) & 7;
  const int ks   = blockIdx.x & 1;
  const int rb = tile * BM;
  if (rb >= seg[NEXP]) return;
  int e = 0;
#pragma unroll
  for (int q = 1; q < NEXP; ++q) if (seg[q] <= rb) e = q;
  const int cnt = counts[e];
  const int rloc0 = rb - seg[e];
  const int k0 = ks * (FFN / 2);
  const int k1 = k0 + (FFN / 2);

  __shared__ int tokL[BM];
  __shared__ float pL[BM];
  __shared__ __align__(16) unsigned short Asm[2][BM*BK];
  __shared__ __align__(16) unsigned short Bsm[2][BM*BK];

  const int tid = threadIdx.x;
  if (tid < BM) {
    int rl = rloc0 + tid;
    if (rl < cnt) {
      int tk = lists[e * NTOK + rl];
      tokL[tid] = tk;
      pL[tid] = probs[tk * NEXP + e];
    } else { tokL[tid] = 0; pL[tid] = 0.f; }
  }
  __syncthreads();

  const int lane = tid & 63;
  const int wid = tid >> 6;
  const int wr = (wid >> 1) * 64;
  const int wc = (wid & 1) * 64;
  const int lr = (lane >> 4) * 4;
  const int lc = lane & 15;
  const int khi = (lane >> 4) * 8;

  const int cw8 = (lane & 3) * 8;
  const int r0 = wid*16 + (lane >> 2);
  const unsigned short* abase[2];
  const unsigned short* bbase[2];
  abase[0] = hbuf + (size_t)(rb + r0)      * FFN + cw8;
  abase[1] = hbuf + (size_t)(rb + 64 + r0) * FFN + cw8;
  bbase[0] = w2t + ((size_t)e * HID + jcol*BN + r0)      * FFN + cw8;
  bbase[1] = w2t + ((size_t)e * HID + jcol*BN + 64 + r0) * FFN + cw8;

  f32x4 acc[4][4];
#pragma unroll
  for (int m = 0; m < 4; ++m)
#pragma unroll
    for (int n = 0; n < 4; ++n)
      acc[m][n] = (f32x4){0.f, 0.f, 0.f, 0.f};

#define STAGE2(buf, kk) do { \
    _Pragma("unroll") \
    for (int i = 0; i < 2; ++i) { \
      GLOAD16(abase[i] + (kk), &Asm[buf][(i*256 + wid*64)*8]); \
      GLOAD16(bbase[i] + (kk), &Bsm[buf][(i*256 + wid*64)*8]); \
    } } while (0)

  STAGE2(0, k0);
  VMCNT0;
  __syncthreads();
  int cur = 0;
  for (int kk = k0; kk < k1; kk += BK) {
    if (kk + BK < k1) STAGE2(cur ^ 1, kk + BK);
    half8 af[4], bf[4];
#pragma unroll
    for (int m = 0; m < 4; ++m)
      af[m] = *reinterpret_cast<const half8*>(&Asm[cur][(wr + m*16 + lc)*BK + khi]);
#pragma unroll
    for (int n = 0; n < 4; ++n)
      bf[n] = *reinterpret_cast<const half8*>(&Bsm[cur][(wc + n*16 + lc)*BK + khi]);
#pragma unroll
    for (int m = 0; m < 4; ++m)
#pragma unroll
      for (int n = 0; n < 4; ++n)
        acc[m][n] = __builtin_amdgcn_mfma_f32_16x16x32_f16(af[m], bf[n], acc[m][n], 0, 0, 0);
    VMCNT0;              // drain next-tile DMA issued above
    __syncthreads();
    cur ^= 1;
  }
#undef STAGE2

#pragma unroll
  for (int m = 0; m < 4; ++m) {
#pragma unroll
    for (int r = 0; r < 4; ++r) {
      const int lrow = wr + m*16 + lr + r;
      const int rl = rloc0 + lrow;
      if (rl >= cnt) continue;
      const int tok = tokL[lrow];
      const float p = pL[lrow];
      float* op = out + (size_t)tok * HID + jcol*BN + wc + lc;
#pragma unroll
      for (int n = 0; n < 4; ++n)
        atomicAdd(&op[n*16], p * acc[m][n][r]);   // <=4 commutative fp32 adds/element
    }
  }
}

extern "C" void kernel_launch(void* const* d_in, const int* in_sizes, int n_in,
                              void* d_out, int out_size, void* d_ws, size_t ws_size,
                              hipStream_t stream) {
  const float* x  = (const float*)d_in[0];
  const float* rw = (const float*)d_in[1];
  const float* w1 = (const float*)d_in[2];
  const float* w2 = (const float*)d_in[3];
  float* out = (float*)d_out;

  char* ws = (char*)d_ws;
  int*   counts = (int*)(ws + WS_COUNTS);
  int*   seg    = (int*)(ws + WS_SEG);
  float* probs  = (float*)(ws + WS_PROBS);
  int*   lists  = (int*)(ws + WS_LISTS);
  unsigned short* xh   = (unsigned short*)(ws + WS_XH);
  unsigned short* w1t  = (unsigned short*)(ws + WS_W1T);
  unsigned short* w2t  = (unsigned short*)(ws + WS_W2T);
  unsigned short* hbuf = (unsigned short*)(ws + WS_HBUF);

  hipMemsetAsync(ws, 0, 128, stream);                                   // counts+seg
  hipMemsetAsync(d_out, 0, (size_t)NTOK * HID * sizeof(float), stream); // atomic target

  moe_prep<<<8192 + NTOK/4, 256, 0, stream>>>(x, rw, w1, w2, xh, w1t, w2t,
                                              counts, lists, probs);
  moe_segoff<<<1, 64, 0, stream>>>(counts, seg);
  moe_gemm1<<<MAX_TILES * (FFN / BN), 256, 0, stream>>>(xh, w1t, counts, seg, lists, hbuf);
  moe_gemm2<<<MAX_TILES * (HID / BN) * 2, 256, 0, stream>>>(hbuf, w2t, counts, seg, lists, probs, out);
}

// Round 12
// 184.551 us; speedup vs baseline: 1.3462x; 1.0383x over previous
//
#include <hip/hip_runtime.h>
#include <hip/hip_fp16.h>
#include <math.h>

#define NTOK 2048
#define HID  1024
#define FFN  2048
#define NEXP 8

#define BM 128
#define BN 128
#define BK 32             // fp16 K-step; GEMM LDS = 33KB/block -> 4 blocks/CU
#define MAX_TILES 40
#define TLDA 66           // transpose LDS stride (hw): 33 dwords -> +1 bank/row

// workspace layout (bytes)
#define WS_COUNTS 0
#define WS_SEG    32
#define WS_PROBS  128                       // NTOK*NEXP floats = 64KB
#define WS_LISTS  (128 + NTOK*NEXP*4)       // 8*NTOK ints = 64KB
#define WS_XH     262144                    // [NTOK][HID] fp16 = 4MB
#define WS_W1T    (WS_XH + NTOK*HID*2)      // [E][F][H] fp16 = 32MB
#define WS_W2T    (WS_W1T + NEXP*HID*FFN*2) // [E][H][F] fp16 = 32MB
#define WS_HBUF   (WS_W2T + NEXP*HID*FFN*2) // [5120][FFN] fp16 = 20MB

typedef _Float16 half8 __attribute__((ext_vector_type(8)));
typedef float    f32x4 __attribute__((ext_vector_type(4)));

static __device__ __forceinline__ unsigned short f2h_bits(float f) {
  union { _Float16 h; unsigned short u; } v;
  v.h = (_Float16)f;
  return v.u;
}
static __device__ __forceinline__ unsigned pack2(float a, float b) {
  return (unsigned)f2h_bits(a) | ((unsigned)f2h_bits(b) << 16);
}

#define GLOAD16(gsrc, ldst) \
  __builtin_amdgcn_global_load_lds( \
      (const __attribute__((address_space(1))) unsigned int*)(gsrc), \
      (__attribute__((address_space(3))) unsigned int*)(ldst), 16, 0, 0)

// Drain all outstanding global_load_lds DMA writes issued by this wave.
// (Round-5 lesson: do NOT rely on the compiler's vmcnt before s_barrier.)
#define VMCNT0 asm volatile("s_waitcnt vmcnt(0)" ::: "memory")

// ---------------- pipelined 4-tile 64x64 transpose (fp32 -> fp16^T) ----------
// Tile math identical to the verified round-10 kernel; adds: 4 tiles/block,
// global loads for tile t+1 issued before tile t's LDS bounce (latency hides
// under pack+LDS+store), double-buffered LDS, ONE barrier per tile (t+2's
// write to buf[t&1] is ordered after t's read by t+1's barrier).
template<int IS_W1>
static __device__ __forceinline__ void transpose4(
    int t0, const float* __restrict__ wsrc, unsigned short* __restrict__ wdst,
    unsigned short (*Ls)[64*TLDA], int tid)
{
  const int row = tid >> 2, cq = tid & 3;   // read-phase coords
  const int oc  = tid >> 2, rs = tid & 3;   // write-phase coords (oc = src col)
  const int e = t0 >> 9;                    // t0%512 <= 508 -> uniform per block
  const int R = IS_W1 ? HID : FFN;
  const int C = IS_W1 ? FFN : HID;
  const float* src = wsrc + (size_t)e * HID * FFN;
  unsigned short* dst = wdst + (size_t)e * HID * FFN;
  float4 ld[2][4];                          // static-indexed after full unroll

#define TGEOM(tt, r0v, c0v) \
    { const int rem_ = (t0 + (tt)) & 511; \
      r0v = IS_W1 ? ((rem_ >> 5) * 64) : ((rem_ >> 4) * 64); \
      c0v = IS_W1 ? ((rem_ & 31) * 64) : ((rem_ & 15) * 64); }

  {
    int r0, c0; TGEOM(0, r0, c0);
    const float4* sp = reinterpret_cast<const float4*>(
        src + (size_t)(r0 + row) * C + c0 + cq * 16);
#pragma unroll
    for (int j = 0; j < 4; ++j) ld[0][j] = sp[j];
  }
#pragma unroll
  for (int t = 0; t < 4; ++t) {
    if (t < 3) {                            // prefetch next tile (in flight below)
      int r0, c0; TGEOM(t + 1, r0, c0);
      const float4* sp = reinterpret_cast<const float4*>(
          src + (size_t)(r0 + row) * C + c0 + cq * 16);
#pragma unroll
      for (int j = 0; j < 4; ++j) ld[(t + 1) & 1][j] = sp[j];
    }
    {
      unsigned* Ld = reinterpret_cast<unsigned*>(Ls[t & 1]);
      const int dbase = row * (TLDA / 2) + cq * 8;
      const float4 a = ld[t & 1][0], b = ld[t & 1][1];
      const float4 c2 = ld[t & 1][2], d = ld[t & 1][3];
      Ld[dbase + 0] = pack2(a.x, a.y);  Ld[dbase + 1] = pack2(a.z, a.w);
      Ld[dbase + 2] = pack2(b.x, b.y);  Ld[dbase + 3] = pack2(b.z, b.w);
      Ld[dbase + 4] = pack2(c2.x, c2.y); Ld[dbase + 5] = pack2(c2.z, c2.w);
      Ld[dbase + 6] = pack2(d.x, d.y);  Ld[dbase + 7] = pack2(d.z, d.w);
    }
    __syncthreads();
    {
      int r0, c0; TGEOM(t, r0, c0);
      unsigned v[8];
#pragma unroll
      for (int j = 0; j < 8; ++j) {
        unsigned lo = Ls[t & 1][(rs * 16 + 2 * j    ) * TLDA + oc];
        unsigned hi = Ls[t & 1][(rs * 16 + 2 * j + 1) * TLDA + oc];
        v[j] = lo | (hi << 16);
      }
      unsigned short* dp = dst + (size_t)(c0 + oc) * R + r0 + rs * 16;
      *reinterpret_cast<uint4*>(dp)     = (uint4){v[0], v[1], v[2], v[3]};
      *reinterpret_cast<uint4*>(dp + 8) = (uint4){v[4], v[5], v[6], v[7]};
    }
  }
#undef TGEOM
}

// ---------------- launch 1: w1 transpose (pipelined) | router + x->fp16 -----
// bid [0,1024):    w1 tiles 4*bid..4*bid+3
// bid [1024,1536): router, 4 tokens/block (1 wave each) + xh write
__global__ __launch_bounds__(256) void moe_prep1(
    const float* __restrict__ x, const float* __restrict__ rw,
    const float* __restrict__ w1,
    unsigned short* __restrict__ xh, unsigned short* __restrict__ w1t,
    int* __restrict__ counts, int* __restrict__ lists, float* __restrict__ probs)
{
  __shared__ unsigned short Ls[2][64 * TLDA];
  const int bid = blockIdx.x;
  const int tid = threadIdx.x;

  if (bid < 1024) {
    transpose4<1>(bid * 4, w1, w1t, Ls, tid);
    return;
  }
  const int wid = tid >> 6, lane = tid & 63;
  const int t = (bid - 1024) * 4 + wid;
  const float* xr = x + (size_t)t * HID + lane * 16;
  const float4* xp = reinterpret_cast<const float4*>(xr);
  float4 v0 = xp[0], v1 = xp[1], v2 = xp[2], v3 = xp[3];
  float xv[16] = {v0.x,v0.y,v0.z,v0.w, v1.x,v1.y,v1.z,v1.w,
                  v2.x,v2.y,v2.z,v2.w, v3.x,v3.y,v3.z,v3.w};
  float acc[NEXP];
#pragma unroll
  for (int e = 0; e < NEXP; ++e) acc[e] = 0.f;
#pragma unroll
  for (int j = 0; j < 16; ++j) {
    const float4* rp = reinterpret_cast<const float4*>(rw + (size_t)(lane*16 + j) * NEXP);
    float4 a = rp[0], b = rp[1];
    acc[0] += xv[j]*a.x; acc[1] += xv[j]*a.y; acc[2] += xv[j]*a.z; acc[3] += xv[j]*a.w;
    acc[4] += xv[j]*b.x; acc[5] += xv[j]*b.y; acc[6] += xv[j]*b.z; acc[7] += xv[j]*b.w;
  }
#pragma unroll
  for (int off = 32; off > 0; off >>= 1) {
#pragma unroll
    for (int e = 0; e < NEXP; ++e) acc[e] += __shfl_down(acc[e], off);
  }
  unsigned short* xd = xh + (size_t)t * HID + lane * 16;
  *reinterpret_cast<uint4*>(xd) =
      (uint4){pack2(v0.x,v0.y), pack2(v0.z,v0.w), pack2(v1.x,v1.y), pack2(v1.z,v1.w)};
  *reinterpret_cast<uint4*>(xd + 8) =
      (uint4){pack2(v2.x,v2.y), pack2(v2.z,v2.w), pack2(v3.x,v3.y), pack2(v3.z,v3.w)};
  if (lane == 0) {
    float m = acc[0];
#pragma unroll
    for (int e = 1; e < NEXP; ++e) m = fmaxf(m, acc[e]);
    float p[NEXP];
#pragma unroll
    for (int e = 0; e < NEXP; ++e) p[e] = expf(acc[e] - m);
    int i0 = 0;
#pragma unroll
    for (int e = 1; e < NEXP; ++e) if (p[e] > p[i0]) i0 = e;
    int i1 = -1;
#pragma unroll
    for (int e = 0; e < NEXP; ++e) {
      if (e == i0) continue;
      if (i1 < 0 || p[e] > p[i1]) i1 = e;
    }
    const float inv = 1.f / (p[i0] + p[i1]);
    probs[t * NEXP + i0] = p[i0] * inv;
    probs[t * NEXP + i1] = p[i1] * inv;
    int pos0 = atomicAdd(&counts[i0], 1); lists[i0 * NTOK + pos0] = t;
    int pos1 = atomicAdd(&counts[i1], 1); lists[i1 * NTOK + pos1] = t;
  }
}

// ---------------- padded segment offsets ----------------
__global__ void moe_segoff(const int* __restrict__ counts, int* __restrict__ seg) {
  if (threadIdx.x == 0 && blockIdx.x == 0) {
    int run = 0;
    for (int e = 0; e < NEXP; ++e) {
      seg[e] = run;
      run += ((counts[e] + BM - 1) / BM) * BM;
    }
    seg[NEXP] = run;
  }
}

// ---------------- launch 2: GEMM1 | w2 transpose (independent, co-resident) --
// bid [0,640):     gemm1 h = gelu(xh[tok] @ w1t[e]^T) -> fp16 hbuf
//                  (640 = MAX_TILES*16 -- MUST cover all 40 padded row-tiles;
//                   round-11 bug: 512 left tiles 32..39 unwritten)
// bid [640,1664):  w2 tiles 4*(bid-640)..+3  (concurrent with gemm1 MFMA)
__global__ __launch_bounds__(256) void moe_k2(
    const unsigned short* __restrict__ xh, const unsigned short* __restrict__ w1t,
    const float* __restrict__ w2, unsigned short* __restrict__ w2t,
    const int* __restrict__ counts, const int* __restrict__ seg,
    const int* __restrict__ lists, unsigned short* __restrict__ hbuf)
{
  __shared__ __align__(16) unsigned short SMEM[4 * BM * BK];   // 32KB (overlaid)
  __shared__ int tokL[BM];
  const int bid = blockIdx.x;
  const int tid = threadIdx.x;

  if (bid >= MAX_TILES * 16) {
    transpose4<0>((bid - MAX_TILES * 16) * 4, w2, w2t,
                  reinterpret_cast<unsigned short(*)[64 * TLDA]>(SMEM), tid);
    return;
  }

  const int tile = bid >> 4;
  const int jcol = bid & 15;
  const int rb = tile * BM;
  if (rb >= seg[NEXP]) return;
  int e = 0;
#pragma unroll
  for (int q = 1; q < NEXP; ++q) if (seg[q] <= rb) e = q;
  const int cnt = counts[e];
  const int rloc0 = rb - seg[e];

  unsigned short (*Asm)[BM*BK] = reinterpret_cast<unsigned short(*)[BM*BK]>(SMEM);
  unsigned short (*Bsm)[BM*BK] = reinterpret_cast<unsigned short(*)[BM*BK]>(SMEM + 2*BM*BK);

  if (tid < BM) {
    int rl = rloc0 + tid;
    tokL[tid] = (rl < cnt) ? lists[e * NTOK + rl] : 0;
  }
  __syncthreads();

  const int lane = tid & 63;
  const int wid = tid >> 6;
  const int wr = (wid >> 1) * 64;
  const int wc = (wid & 1) * 64;
  const int lr = (lane >> 4) * 4;
  const int lc = lane & 15;
  const int khi = (lane >> 4) * 8;

  const int cw8 = (lane & 3) * 8;
  const int r0 = wid*16 + (lane >> 2);
  const unsigned short* abase[2];
  const unsigned short* bbase[2];
  abase[0] = xh + (size_t)tokL[r0]      * HID + cw8;
  abase[1] = xh + (size_t)tokL[64 + r0] * HID + cw8;
  bbase[0] = w1t + ((size_t)e * FFN + jcol*BN + r0)      * HID + cw8;
  bbase[1] = w1t + ((size_t)e * FFN + jcol*BN + 64 + r0) * HID + cw8;

  f32x4 acc[4][4];
#pragma unroll
  for (int m = 0; m < 4; ++m)
#pragma unroll
    for (int n = 0; n < 4; ++n)
      acc[m][n] = (f32x4){0.f, 0.f, 0.f, 0.f};

#define STAGE1(buf, kk) do { \
    _Pragma("unroll") \
    for (int i = 0; i < 2; ++i) { \
      GLOAD16(abase[i] + (kk), &Asm[buf][(i*256 + wid*64)*8]); \
      GLOAD16(bbase[i] + (kk), &Bsm[buf][(i*256 + wid*64)*8]); \
    } } while (0)

  STAGE1(0, 0);
  VMCNT0;
  __syncthreads();
  int cur = 0;
  for (int kk = 0; kk < HID; kk += BK) {
    if (kk + BK < HID) STAGE1(cur ^ 1, kk + BK);
    half8 af[4], bf[4];
#pragma unroll
    for (int m = 0; m < 4; ++m)
      af[m] = *reinterpret_cast<const half8*>(&Asm[cur][(wr + m*16 + lc)*BK + khi]);
#pragma unroll
    for (int n = 0; n < 4; ++n)
      bf[n] = *reinterpret_cast<const half8*>(&Bsm[cur][(wc + n*16 + lc)*BK + khi]);
#pragma unroll
    for (int m = 0; m < 4; ++m)
#pragma unroll
      for (int n = 0; n < 4; ++n)
        acc[m][n] = __builtin_amdgcn_mfma_f32_16x16x32_f16(af[m], bf[n], acc[m][n], 0, 0, 0);
    VMCNT0;              // drain next-tile DMA issued above (overlapped with MFMA)
    __syncthreads();
    cur ^= 1;
  }
#undef STAGE1

  // Unconditional: padding rows get deterministic values (token-0 data),
  // so gemm2 never reads poison from hbuf.
#pragma unroll
  for (int m = 0; m < 4; ++m) {
#pragma unroll
    for (int r = 0; r < 4; ++r) {
      unsigned short* hp = hbuf + (size_t)(rb + wr + m*16 + lr + r) * FFN + jcol*BN + wc + lc;
#pragma unroll
      for (int n = 0; n < 4; ++n) {
        float v = acc[m][n][r];
        float g = 0.5f * v * (1.f + erff(v * 0.70710678118f));   // exact erf-gelu
        hp[n*16] = f2h_bits(g);
      }
    }
  }
}

// ---------------- GEMM2: out[tok] += p * (hbuf @ w2t[e]^T), split-K x2 ----------------
__global__ __launch_bounds__(256) void moe_gemm2(
    const unsigned short* __restrict__ hbuf, const unsigned short* __restrict__ w2t,
    const int* __restrict__ counts, const int* __restrict__ seg,
    const int* __restrict__ lists, const float* __restrict__ probs,
    float* __restrict__ out)
{
  const int tile = blockIdx.x >> 4;
  const int jcol = (blockIdx.x >> 1) & 7;
  const int ks   = blockIdx.x & 1;
  const int rb = tile * BM;
  if (rb >= seg[NEXP]) return;
  int e = 0;
#pragma unroll
  for (int q = 1; q < NEXP; ++q) if (seg[q] <= rb) e = q;
  const int cnt = counts[e];
  const int rloc0 = rb - seg[e];
  const int k0 = ks * (FFN / 2);
  const int k1 = k0 + (FFN / 2);

  __shared__ int tokL[BM];
  __shared__ float pL[BM];
  __shared__ __align__(16) unsigned short Asm[2][BM*BK];
  __shared__ __align__(16) unsigned short Bsm[2][BM*BK];

  const int tid = threadIdx.x;
  if (tid < BM) {
    int rl = rloc0 + tid;
    if (rl < cnt) {
      int tk = lists[e * NTOK + rl];
      tokL[tid] = tk;
      pL[tid] = probs[tk * NEXP + e];
    } else { tokL[tid] = 0; pL[tid] = 0.f; }
  }
  __syncthreads();

  const int lane = tid & 63;
  const int wid = tid >> 6;
  const int wr = (wid >> 1) * 64;
  const int wc = (wid & 1) * 64;
  const int lr = (lane >> 4) * 4;
  const int lc = lane & 15;
  const int khi = (lane >> 4) * 8;

  const int cw8 = (lane & 3) * 8;
  const int r0 = wid*16 + (lane >> 2);
  const unsigned short* abase[2];
  const unsigned short* bbase[2];
  abase[0] = hbuf + (size_t)(rb + r0)      * FFN + cw8;
  abase[1] = hbuf + (size_t)(rb + 64 + r0) * FFN + cw8;
  bbase[0] = w2t + ((size_t)e * HID + jcol*BN + r0)      * FFN + cw8;
  bbase[1] = w2t + ((size_t)e * HID + jcol*BN + 64 + r0) * FFN + cw8;

  f32x4 acc[4][4];
#pragma unroll
  for (int m = 0; m < 4; ++m)
#pragma unroll
    for (int n = 0; n < 4; ++n)
      acc[m][n] = (f32x4){0.f, 0.f, 0.f, 0.f};

#define STAGE2(buf, kk) do { \
    _Pragma("unroll") \
    for (int i = 0; i < 2; ++i) { \
      GLOAD16(abase[i] + (kk), &Asm[buf][(i*256 + wid*64)*8]); \
      GLOAD16(bbase[i] + (kk), &Bsm[buf][(i*256 + wid*64)*8]); \
    } } while (0)

  STAGE2(0, k0);
  VMCNT0;
  __syncthreads();
  int cur = 0;
  for (int kk = k0; kk < k1; kk += BK) {
    if (kk + BK < k1) STAGE2(cur ^ 1, kk + BK);
    half8 af[4], bf[4];
#pragma unroll
    for (int m = 0; m < 4; ++m)
      af[m] = *reinterpret_cast<const half8*>(&Asm[cur][(wr + m*16 + lc)*BK + khi]);
#pragma unroll
    for (int n = 0; n < 4; ++n)
      bf[n] = *reinterpret_cast<const half8*>(&Bsm[cur][(wc + n*16 + lc)*BK + khi]);
#pragma unroll
    for (int m = 0; m < 4; ++m)
#pragma unroll
      for (int n = 0; n < 4; ++n)
        acc[m][n] = __builtin_amdgcn_mfma_f32_16x16x32_f16(af[m], bf[n], acc[m][n], 0, 0, 0);
    VMCNT0;              // drain next-tile DMA issued above
    __syncthreads();
    cur ^= 1;
  }
#undef STAGE2

#pragma unroll
  for (int m = 0; m < 4; ++m) {
#pragma unroll
    for (int r = 0; r < 4; ++r) {
      const int lrow = wr + m*16 + lr + r;
      const int rl = rloc0 + lrow;
      if (rl >= cnt) continue;
      const int tok = tokL[lrow];
      const float p = pL[lrow];
      float* op = out + (size_t)tok * HID + jcol*BN + wc + lc;
#pragma unroll
      for (int n = 0; n < 4; ++n)
        atomicAdd(&op[n*16], p * acc[m][n][r]);   // <=4 commutative fp32 adds/element
    }
  }
}

extern "C" void kernel_launch(void* const* d_in, const int* in_sizes, int n_in,
                              void* d_out, int out_size, void* d_ws, size_t ws_size,
                              hipStream_t stream) {
  const float* x  = (const float*)d_in[0];
  const float* rw = (const float*)d_in[1];
  const float* w1 = (const float*)d_in[2];
  const float* w2 = (const float*)d_in[3];
  float* out = (float*)d_out;

  char* ws = (char*)d_ws;
  int*   counts = (int*)(ws + WS_COUNTS);
  int*   seg    = (int*)(ws + WS_SEG);
  float* probs  = (float*)(ws + WS_PROBS);
  int*   lists  = (int*)(ws + WS_LISTS);
  unsigned short* xh   = (unsigned short*)(ws + WS_XH);
  unsigned short* w1t  = (unsigned short*)(ws + WS_W1T);
  unsigned short* w2t  = (unsigned short*)(ws + WS_W2T);
  unsigned short* hbuf = (unsigned short*)(ws + WS_HBUF);

  hipMemsetAsync(ws, 0, 128, stream);                                   // counts+seg
  hipMemsetAsync(d_out, 0, (size_t)NTOK * HID * sizeof(float), stream); // atomic target

  moe_prep1<<<1024 + NTOK/4, 256, 0, stream>>>(x, rw, w1, xh, w1t,
                                               counts, lists, probs);
  moe_segoff<<<1, 64, 0, stream>>>(counts, seg);
  moe_k2<<<MAX_TILES * 16 + 1024, 256, 0, stream>>>(xh, w1t, w2, w2t,
                                                    counts, seg, lists, hbuf);
  moe_gemm2<<<MAX_TILES * (HID / BN) * 2, 256, 0, stream>>>(hbuf, w2t, counts, seg, lists, probs, out);
}

// Round 15
// 176.180 us; speedup vs baseline: 1.4102x; 1.0475x over previous
//
#include <hip/hip_runtime.h>
#include <hip/hip_fp16.h>
#include <math.h>

#define NTOK 2048
#define HID  1024
#define FFN  2048
#define NEXP 8

#define BM 128
#define BN 128
#define BK 32
#define LDK 36            // Bsm col stride (hw); 72B -> b64-aligned for all cols
#define MAX_TILES 40

// workspace layout (bytes)
#define WS_COUNTS 0
#define WS_SEG    32
#define WS_PROBS  128                       // NTOK*NEXP floats
#define WS_LISTS  (128 + NTOK*NEXP*4)       // 8*NTOK ints
#define WS_XH     262144                    // [NTOK][HID] fp16 = 4MB
#define WS_HBUF   (WS_XH + NTOK*HID*2)      // [5120][FFN] fp16 = 20MB

typedef _Float16 half8 __attribute__((ext_vector_type(8)));
typedef __fp16   fp16x2 __attribute__((ext_vector_type(2)));  // cvt_pkrtz return type
typedef float    f32x4 __attribute__((ext_vector_type(4)));
typedef unsigned long long u64;

static __device__ __forceinline__ unsigned short f2h_bits(float f) {
  union { _Float16 h; unsigned short u; } v;
  v.h = (_Float16)f;
  return v.u;
}
static __device__ __forceinline__ unsigned pack2(float a, float b) {
  return (unsigned)f2h_bits(a) | ((unsigned)f2h_bits(b) << 16);
}
static __device__ __forceinline__ unsigned cvt2(float a, float b) {
  union { fp16x2 h; unsigned u; } t;
  t.h = __builtin_amdgcn_cvt_pkrtz(a, b);   // v_cvt_pkrtz_f16_f32, 1 instr (RTZ)
  return t.u;
}

#define GLOAD16(gsrc, ldst) \
  __builtin_amdgcn_global_load_lds( \
      (const __attribute__((address_space(1))) unsigned int*)(gsrc), \
      (__attribute__((address_space(3))) unsigned int*)(ldst), 16, 0, 0)

// Drain outstanding global_load_lds DMA (round-5 lesson: never rely on the
// compiler's vmcnt before s_barrier).
#define VMCNT0 asm volatile("s_waitcnt vmcnt(0)" ::: "memory")

// ---------------- prep: router + x->fp16 (one wave per token) ----------------
__global__ __launch_bounds__(256) void moe_prep(
    const float* __restrict__ x, const float* __restrict__ rw,
    unsigned short* __restrict__ xh,
    int* __restrict__ counts, int* __restrict__ lists, float* __restrict__ probs)
{
  const int tid = threadIdx.x;
  const int wid = tid >> 6, lane = tid & 63;
  const int t = blockIdx.x * 4 + wid;

  const float* xr = x + (size_t)t * HID + lane * 16;
  const float4* xp = reinterpret_cast<const float4*>(xr);
  float4 v0 = xp[0], v1 = xp[1], v2 = xp[2], v3 = xp[3];
  float xv[16] = {v0.x,v0.y,v0.z,v0.w, v1.x,v1.y,v1.z,v1.w,
                  v2.x,v2.y,v2.z,v2.w, v3.x,v3.y,v3.z,v3.w};
  float acc[NEXP];
#pragma unroll
  for (int e = 0; e < NEXP; ++e) acc[e] = 0.f;
#pragma unroll
  for (int j = 0; j < 16; ++j) {
    const float4* rp = reinterpret_cast<const float4*>(rw + (size_t)(lane*16 + j) * NEXP);
    float4 a = rp[0], b = rp[1];
    acc[0] += xv[j]*a.x; acc[1] += xv[j]*a.y; acc[2] += xv[j]*a.z; acc[3] += xv[j]*a.w;
    acc[4] += xv[j]*b.x; acc[5] += xv[j]*b.y; acc[6] += xv[j]*b.z; acc[7] += xv[j]*b.w;
  }
#pragma unroll
  for (int off = 32; off > 0; off >>= 1) {
#pragma unroll
    for (int e = 0; e < NEXP; ++e) acc[e] += __shfl_down(acc[e], off);
  }
  unsigned short* xd = xh + (size_t)t * HID + lane * 16;
  *reinterpret_cast<uint4*>(xd) =
      (uint4){pack2(v0.x,v0.y), pack2(v0.z,v0.w), pack2(v1.x,v1.y), pack2(v1.z,v1.w)};
  *reinterpret_cast<uint4*>(xd + 8) =
      (uint4){pack2(v2.x,v2.y), pack2(v2.z,v2.w), pack2(v3.x,v3.y), pack2(v3.z,v3.w)};
  if (lane == 0) {
    float m = acc[0];
#pragma unroll
    for (int e = 1; e < NEXP; ++e) m = fmaxf(m, acc[e]);
    float p[NEXP];
#pragma unroll
    for (int e = 0; e < NEXP; ++e) p[e] = expf(acc[e] - m);
    int i0 = 0;
#pragma unroll
    for (int e = 1; e < NEXP; ++e) if (p[e] > p[i0]) i0 = e;
    int i1 = -1;
#pragma unroll
    for (int e = 0; e < NEXP; ++e) {
      if (e == i0) continue;
      if (i1 < 0 || p[e] > p[i1]) i1 = e;
    }
    const float inv = 1.f / (p[i0] + p[i1]);
    probs[t * NEXP + i0] = p[i0] * inv;
    probs[t * NEXP + i1] = p[i1] * inv;
    int pos0 = atomicAdd(&counts[i0], 1); lists[i0 * NTOK + pos0] = t;
    int pos1 = atomicAdd(&counts[i1], 1); lists[i1 * NTOK + pos1] = t;
  }
}

// ---------------- padded segment offsets ----------------
__global__ void moe_segoff(const int* __restrict__ counts, int* __restrict__ seg) {
  if (threadIdx.x == 0 && blockIdx.x == 0) {
    int run = 0;
    for (int e = 0; e < NEXP; ++e) {
      seg[e] = run;
      run += ((counts[e] + BM - 1) / BM) * BM;
    }
    seg[NEXP] = run;
  }
}

// ---------------- GEMM1: h = gelu(xh[tok] @ w1[e]) -> fp16 hbuf --------------
// A: fp16 gathered rows via global_load_lds (linear LDS).  B: w1 fp32 read
// DIRECTLY in native [H][F] layout -- per thread a 4(k)x4(f) block: 4 fully-
// coalesced float4 loads, 8 cvt_pkrtz, 4 ds_write_b64 into Bsm[col][k].
__global__ __launch_bounds__(256) void moe_gemm1(
    const unsigned short* __restrict__ xh, const float* __restrict__ w1,
    const int* __restrict__ counts, const int* __restrict__ seg,
    const int* __restrict__ lists, unsigned short* __restrict__ hbuf)
{
  const int tile = blockIdx.x >> 4;
  const int jcol = blockIdx.x & 15;
  const int rb = tile * BM;
  if (rb >= seg[NEXP]) return;
  int e = 0;
#pragma unroll
  for (int q = 1; q < NEXP; ++q) if (seg[q] <= rb) e = q;
  const int cnt = counts[e];
  const int rloc0 = rb - seg[e];

  __shared__ int tokL[BM];
  __shared__ __align__(16) unsigned short Asm[2][BM*BK];   // 8KB each
  __shared__ __align__(16) unsigned short Bsm[2][BN*LDK];  // 9KB each

  const int tid = threadIdx.x;
  if (tid < BM) {
    int rl = rloc0 + tid;
    tokL[tid] = (rl < cnt) ? lists[e * NTOK + rl] : 0;
  }
  __syncthreads();

  const int lane = tid & 63;
  const int wid = tid >> 6;
  const int wr = (wid >> 1) * 64;
  const int wc = (wid & 1) * 64;
  const int lr = (lane >> 4) * 4;
  const int lc = lane & 15;
  const int khi = (lane >> 4) * 8;

  // A staging (DMA)
  const int cw8 = (lane & 3) * 8;
  const int r0 = wid*16 + (lane >> 2);
  const unsigned short* abase[2];
  abase[0] = xh + (size_t)tokL[r0]      * HID + cw8;
  abase[1] = xh + (size_t)tokL[64 + r0] * HID + cw8;

  // B staging: thread -> (kb, fb): k rows kb*4..+3, f cols fb*4..+3
  const int kb = tid >> 5;          // 0..7
  const int fb = tid & 31;          // 0..31
  const float* bbase = w1 + (size_t)e * HID * FFN + (size_t)jcol * BN + fb * 4;

  f32x4 acc[4][4];
#pragma unroll
  for (int m = 0; m < 4; ++m)
#pragma unroll
    for (int n = 0; n < 4; ++n)
      acc[m][n] = (f32x4){0.f, 0.f, 0.f, 0.f};

  f32x4 bld[4];

#define LOADB1(kk) do { \
    _Pragma("unroll") \
    for (int j = 0; j < 4; ++j) \
      bld[j] = *reinterpret_cast<const f32x4*>(bbase + (size_t)((kk) + kb*4 + j) * FFN); \
  } while (0)

#define STAGEA(buf, kk) do { \
    GLOAD16(abase[0] + (kk), &Asm[buf][(wid*64)*8]); \
    GLOAD16(abase[1] + (kk), &Asm[buf][(256 + wid*64)*8]); \
  } while (0)

#define CVTB(buf) do { \
    _Pragma("unroll") \
    for (int i3 = 0; i3 < 4; ++i3) { \
      uint2 wv; \
      wv.x = cvt2(bld[0][i3], bld[1][i3]); \
      wv.y = cvt2(bld[2][i3], bld[3][i3]); \
      *reinterpret_cast<uint2*>(&Bsm[buf][(fb*4 + i3)*LDK + kb*4]) = wv; \
    } } while (0)

  LOADB1(0);
  STAGEA(0, 0);
  int cur = 0;
  for (int kk = 0; kk < HID; kk += BK) {
    CVTB(cur);                       // bld(kk) -> Bsm[cur]
    VMCNT0;                          // A-DMA for Asm[cur] complete
    __syncthreads();                 // publish Asm[cur] + Bsm[cur]
    if (kk + BK < HID) {             // issue next-tile loads; land under MFMA
      LOADB1(kk + BK);
      STAGEA(cur ^ 1, kk + BK);
    }
    half8 af[4], bf[4];
#pragma unroll
    for (int m = 0; m < 4; ++m)
      af[m] = *reinterpret_cast<const half8*>(&Asm[cur][(wr + m*16 + lc)*BK + khi]);
#pragma unroll
    for (int n = 0; n < 4; ++n) {
      union { u64 q[2]; half8 h; } t;
      const unsigned short* bp = &Bsm[cur][(wc + n*16 + lc)*LDK + khi];
      t.q[0] = *reinterpret_cast<const u64*>(bp);
      t.q[1] = *reinterpret_cast<const u64*>(bp + 4);
      bf[n] = t.h;
    }
#pragma unroll
    for (int m = 0; m < 4; ++m)
#pragma unroll
      for (int n = 0; n < 4; ++n)
        acc[m][n] = __builtin_amdgcn_mfma_f32_16x16x32_f16(af[m], bf[n], acc[m][n], 0, 0, 0);
    cur ^= 1;
  }
#undef LOADB1
#undef CVTB

  // Unconditional: padding rows get deterministic values (token-0 data),
  // so gemm2 never reads poison from hbuf.
#pragma unroll
  for (int m = 0; m < 4; ++m) {
#pragma unroll
    for (int r = 0; r < 4; ++r) {
      unsigned short* hp = hbuf + (size_t)(rb + wr + m*16 + lr + r) * FFN + jcol*BN + wc + lc;
#pragma unroll
      for (int n = 0; n < 4; ++n) {
        float v = acc[m][n][r];
        float g = 0.5f * v * (1.f + erff(v * 0.70710678118f));   // exact erf-gelu
        hp[n*16] = f2h_bits(g);
      }
    }
  }
}

// ---------------- GEMM2: out[tok] += p * (hbuf @ w2[e]), split-K x2 ----------
__global__ __launch_bounds__(256) void moe_gemm2(
    const unsigned short* __restrict__ hbuf, const float* __restrict__ w2,
    const int* __restrict__ counts, const int* __restrict__ seg,
    const int* __restrict__ lists, const float* __restrict__ probs,
    float* __restrict__ out)
{
  const int tile = blockIdx.x >> 4;
  const int jcol = (blockIdx.x >> 1) & 7;
  const int ks   = blockIdx.x & 1;
  const int rb = tile * BM;
  if (rb >= seg[NEXP]) return;
  int e = 0;
#pragma unroll
  for (int q = 1; q < NEXP; ++q) if (seg[q] <= rb) e = q;
  const int cnt = counts[e];
  const int rloc0 = rb - seg[e];
  const int k0 = ks * (FFN / 2);
  const int k1 = k0 + (FFN / 2);

  __shared__ int tokL[BM];
  __shared__ float pL[BM];
  __shared__ __align__(16) unsigned short Asm[2][BM*BK];
  __shared__ __align__(16) unsigned short Bsm[2][BN*LDK];

  const int tid = threadIdx.x;
  if (tid < BM) {
    int rl = rloc0 + tid;
    if (rl < cnt) {
      int tk = lists[e * NTOK + rl];
      tokL[tid] = tk;
      pL[tid] = probs[tk * NEXP + e];
    } else { tokL[tid] = 0; pL[tid] = 0.f; }
  }
  __syncthreads();

  const int lane = tid & 63;
  const int wid = tid >> 6;
  const int wr = (wid >> 1) * 64;
  const int wc = (wid & 1) * 64;
  const int lr = (lane >> 4) * 4;
  const int lc = lane & 15;
  const int khi = (lane >> 4) * 8;

  const int cw8 = (lane & 3) * 8;
  const int r0 = wid*16 + (lane >> 2);
  const unsigned short* abase[2];
  abase[0] = hbuf + (size_t)(rb + r0)      * FFN + cw8;
  abase[1] = hbuf + (size_t)(rb + 64 + r0) * FFN + cw8;

  const int kb = tid >> 5;
  const int fb = tid & 31;
  const float* bbase = w2 + (size_t)e * FFN * HID + (size_t)jcol * BN + fb * 4;

  f32x4 acc[4][4];
#pragma unroll
  for (int m = 0; m < 4; ++m)
#pragma unroll
    for (int n = 0; n < 4; ++n)
      acc[m][n] = (f32x4){0.f, 0.f, 0.f, 0.f};

  f32x4 bld[4];

#define LOADB2(kk) do { \
    _Pragma("unroll") \
    for (int j = 0; j < 4; ++j) \
      bld[j] = *reinterpret_cast<const f32x4*>(bbase + (size_t)((kk) + kb*4 + j) * HID); \
  } while (0)

#define CVTB(buf) do { \
    _Pragma("unroll") \
    for (int i3 = 0; i3 < 4; ++i3) { \
      uint2 wv; \
      wv.x = cvt2(bld[0][i3], bld[1][i3]); \
      wv.y = cvt2(bld[2][i3], bld[3][i3]); \
      *reinterpret_cast<uint2*>(&Bsm[buf][(fb*4 + i3)*LDK + kb*4]) = wv; \
    } } while (0)

  LOADB2(k0);
  STAGEA(0, k0);
  int cur = 0;
  for (int kk = k0; kk < k1; kk += BK) {
    CVTB(cur);
    VMCNT0;
    __syncthreads();
    if (kk + BK < k1) {
      LOADB2(kk + BK);
      STAGEA(cur ^ 1, kk + BK);
    }
    half8 af[4], bf[4];
#pragma unroll
    for (int m = 0; m < 4; ++m)
      af[m] = *reinterpret_cast<const half8*>(&Asm[cur][(wr + m*16 + lc)*BK + khi]);
#pragma unroll
    for (int n = 0; n < 4; ++n) {
      union { u64 q[2]; half8 h; } t;
      const unsigned short* bp = &Bsm[cur][(wc + n*16 + lc)*LDK + khi];
      t.q[0] = *reinterpret_cast<const u64*>(bp);
      t.q[1] = *reinterpret_cast<const u64*>(bp + 4);
      bf[n] = t.h;
    }
#pragma unroll
    for (int m = 0; m < 4; ++m)
#pragma unroll
      for (int n = 0; n < 4; ++n)
        acc[m][n] = __builtin_amdgcn_mfma_f32_16x16x32_f16(af[m], bf[n], acc[m][n], 0, 0, 0);
    cur ^= 1;
  }
#undef LOADB2
#undef CVTB
#undef STAGEA

#pragma unroll
  for (int m = 0; m < 4; ++m) {
#pragma unroll
    for (int r = 0; r < 4; ++r) {
      const int lrow = wr + m*16 + lr + r;
      const int rl = rloc0 + lrow;
      if (rl >= cnt) continue;
      const int tok = tokL[lrow];
      const float p = pL[lrow];
      float* op = out + (size_t)tok * HID + jcol*BN + wc + lc;
#pragma unroll
      for (int n = 0; n < 4; ++n)
        atomicAdd(&op[n*16], p * acc[m][n][r]);   // <=4 commutative fp32 adds/element
    }
  }
}

extern "C" void kernel_launch(void* const* d_in, const int* in_sizes, int n_in,
                              void* d_out, int out_size, void* d_ws, size_t ws_size,
                              hipStream_t stream) {
  const float* x  = (const float*)d_in[0];
  const float* rw = (const float*)d_in[1];
  const float* w1 = (const float*)d_in[2];
  const float* w2 = (const float*)d_in[3];
  float* out = (float*)d_out;

  char* ws = (char*)d_ws;
  int*   counts = (int*)(ws + WS_COUNTS);
  int*   seg    = (int*)(ws + WS_SEG);
  float* probs  = (float*)(ws + WS_PROBS);
  int*   lists  = (int*)(ws + WS_LISTS);
  unsigned short* xh   = (unsigned short*)(ws + WS_XH);
  unsigned short* hbuf = (unsigned short*)(ws + WS_HBUF);

  hipMemsetAsync(ws, 0, 128, stream);                                   // counts+seg
  hipMemsetAsync(d_out, 0, (size_t)NTOK * HID * sizeof(float), stream); // atomic target

  moe_prep<<<NTOK/4, 256, 0, stream>>>(x, rw, xh, counts, lists, probs);
  moe_segoff<<<1, 64, 0, stream>>>(counts, seg);
  moe_gemm1<<<MAX_TILES * 16, 256, 0, stream>>>(xh, w1, counts, seg, lists, hbuf);
  moe_gemm2<<<MAX_TILES * 8 * 2, 256, 0, stream>>>(hbuf, w2, counts, seg, lists, probs, out);
}